// Round 3
// baseline (91.038 us; speedup 1.0000x reference)
//
#include <hip/hip_runtime.h>
#include <math.h>

#define HIDDEN   100
#define NCLASS   4
#define MAXCHAIN 256
#define PAD      108   // LDS row stride (floats); 432B: b128 lane reads tile all 32 banks (3i mod 8 coprime)
#define NWORDS   40
#define VOCAB    50000
#define NBLK     48
#define NTHR     512
#define ALDS_MAX 16    // chain nodes of a[] cached in LDS (reuses dead P region)

// ws layout: byte 0: int done; byte 1024: float a[MAXCHAIN][3*HIDDEN]

__global__ __launch_bounds__(NTHR) void k_fused(
    const float* __restrict__ xvals, const int* __restrict__ xidx,
    const int* __restrict__ tree, const int* __restrict__ np_ptr,
    const float* __restrict__ E,
    const float* __restrict__ Wz, const float* __restrict__ bz,
    const float* __restrict__ Wr, const float* __restrict__ br,
    const float* __restrict__ Wh, const float* __restrict__ bh,
    const float* __restrict__ Uz, const float* __restrict__ Ur,
    const float* __restrict__ Uh,
    const float* __restrict__ Wout, const float* __restrict__ bout,
    int* __restrict__ done, float* __restrict__ a, float* __restrict__ out)
{
    extern __shared__ float smem[];
    float* U    = smem;                          // [3][HIDDEN][PAD] = 32400 floats (block 0 only)
    int*   P    = (int*)(smem + 3*HIDDEN*PAD);   // [5000] parent ids (dead after chase)
    float* tail = smem + 3*HIDDEN*PAD + 5000;
    float* h0   = tail;                          // 112
    float* h1   = tail + 112;
    float* zb   = tail + 224;
    float* rh   = tail + 336;
    float* ov   = tail + 448;                    // 16
    float* xep  = tail + 464;                    // 400
    float* xe   = tail + 864;                    // 112
    int*   chain= (int*)(tail + 976);            // 256 ints
    __shared__ int len_s;

    const int t   = threadIdx.x;
    const int bid = blockIdx.x;
    const int npar = np_ptr[0];

    // ---- every block: parents -> LDS, chase ancestor chain of node npar-1 ----
    for (int i = t; i < npar; i += NTHR) P[i] = tree[2 * i];
    __syncthreads();
    if (t == 0) {
        int len = 0, i = npar - 1;
        if (i < 0) i = 0;
        while (i > 0 && len < MAXCHAIN - 1) { chain[len++] = i; i = P[i]; }
        chain[len++] = i;                        // node 0 (zero parent state)
        len_s = len;
    }
    __syncthreads();
    const int L = len_s;

    if (bid == 0) {
        // ---------------- consumer: stage U, spin, run GRU ----------------
        {
            const float4* z4 = (const float4*)Uz;
            const float4* r4 = (const float4*)Ur;
            const float4* g4 = (const float4*)Uh;
            float4 rg[15];
            #pragma unroll
            for (int j = 0; j < 15; ++j) {
                int k = t + j * NTHR;
                if (k < 7500) {
                    const float4* s = (k < 2500) ? (z4 + k)
                                    : (k < 5000) ? (r4 + k - 2500)
                                                 : (g4 + k - 5000);
                    rg[j] = *s;
                }
            }
            #pragma unroll
            for (int j = 0; j < 15; ++j) {
                int k = t + j * NTHR;
                if (k < 7500) {
                    int m = k / 2500, rem = k - m * 2500;
                    int row = rem / 25, c4 = rem - row * 25;
                    *(float4*)(U + (m * HIDDEN + row) * PAD + c4 * 4) = rg[j];
                }
            }
        }
        if (t < 112) { h0[t] = 0.f; h1[t] = 0.f; }
        __syncthreads();
        if (t == 0) {
            while (__hip_atomic_load(done, __ATOMIC_ACQUIRE, __HIP_MEMORY_SCOPE_AGENT) < L)
                __builtin_amdgcn_s_sleep(1);
        }
        __syncthreads();
        (void)__hip_atomic_load(done, __ATOMIC_ACQUIRE, __HIP_MEMORY_SCOPE_AGENT);

        // prefetch a[] into LDS (P region is dead) when it fits
        float* a_lds = (float*)P;                // 5000 floats available
        const bool use_lds = (L <= ALDS_MAX);
        if (use_lds) {
            for (int i = t; i < L * 3 * HIDDEN; i += NTHR) a_lds[i] = a[i];
        }
        __syncthreads();

        float* hc = h0;
        float* hn = h1;
        for (int d = L - 1; d >= 0; --d) {
            const float* ad = (use_lds ? a_lds : a) + d * 3 * HIDDEN;
            if (t < 2 * HIDDEN) {                // z and r rows
                int m = (t >= HIDDEN), i = t - m * HIDDEN;
                float adv = ad[t];
                const float4* ur = (const float4*)(U + (m * HIDDEN + i) * PAD);
                const float4* hv = (const float4*)hc;
                float ac[4] = {0.f, 0.f, 0.f, 0.f};
                #pragma unroll
                for (int k = 0; k < 25; ++k) {
                    float4 u = ur[k], h = hv[k];
                    ac[k & 3] += u.x * h.x + u.y * h.y + u.z * h.z + u.w * h.w;
                }
                float acc = adv + ((ac[0] + ac[1]) + (ac[2] + ac[3]));
                acc = fminf(fmaxf(acc, 0.f), 1.f);           // Hardtanh(0,1)
                if (m == 0) zb[i] = acc;                     // z
                else        rh[i] = acc * hc[i];             // r * parent_h
            }
            __syncthreads();
            if (t < HIDDEN) {                    // c row + state update
                float adv = ad[2 * HIDDEN + t];
                const float4* ur = (const float4*)(U + (2 * HIDDEN + t) * PAD);
                const float4* rv = (const float4*)rh;
                float ac[4] = {0.f, 0.f, 0.f, 0.f};
                #pragma unroll
                for (int k = 0; k < 25; ++k) {
                    float4 u = ur[k], h = rv[k];
                    ac[k & 3] += u.x * h.x + u.y * h.y + u.z * h.z + u.w * h.w;
                }
                float c = tanhf(adv + ((ac[0] + ac[1]) + (ac[2] + ac[3])));
                float z = zb[t];
                hn[t] = (1.f - z) * hc[t] + z * c;
            }
            __syncthreads();
            float* tmp = hc; hc = hn; hn = tmp;
        }

        if (t < NCLASS) {
            float acc = bout[t];
            const float* row = Wout + t * HIDDEN;
            for (int j = 0; j < HIDDEN; ++j) acc += row[j] * hc[j];
            ov[t] = acc;
        }
        __syncthreads();
        if (t == 0) {
            float mx = fmaxf(fmaxf(ov[0], ov[1]), fmaxf(ov[2], ov[3]));
            float e0 = expf(ov[0] - mx), e1 = expf(ov[1] - mx);
            float e2 = expf(ov[2] - mx), e3 = expf(ov[3] - mx);
            float s = e0 + e1 + e2 + e3;
            out[0] = e0 / s; out[1] = e1 / s; out[2] = e2 / s; out[3] = e3 / s;
        }
    } else {
        // ---------------- producers: gather + W matvec per chain node ----------------
        for (int d = bid - 1; d < L; d += NBLK - 1) {
            int c = chain[d];
            if (t < 4 * HIDDEN) {                // (h, word-group) units, 10 ILP loads each
                int h = t >> 2, wg = t & 3;
                const int*   ixp = xidx  + (size_t)c * NWORDS + wg * (NWORDS / 4);
                const float* vp  = xvals + (size_t)c * NWORDS + wg * (NWORDS / 4);
                int   ix[NWORDS / 4];
                float vv[NWORDS / 4];
                #pragma unroll
                for (int w = 0; w < NWORDS / 4; ++w) ix[w] = ixp[w];
                #pragma unroll
                for (int w = 0; w < NWORDS / 4; ++w) vv[w] = vp[w];
                const float* Eh = E + (size_t)h * VOCAB;
                float s0 = 0.f, s1 = 0.f;
                #pragma unroll
                for (int w = 0; w < NWORDS / 4; ++w) {
                    float p = vv[w] * Eh[ix[w]];
                    if (w & 1) s1 += p; else s0 += p;
                }
                xep[t] = s0 + s1;
            }
            __syncthreads();
            if (t < HIDDEN) {
                float4 p = ((const float4*)xep)[t];
                xe[t] = (p.x + p.y) + (p.z + p.w);
            }
            __syncthreads();
            if (t < 3 * HIDDEN) {                // a_m = W_m @ xe + b_m
                int m = t / HIDDEN, i = t - m * HIDDEN;
                const float* Wm = (m == 0 ? Wz : (m == 1 ? Wr : Wh));
                const float* bm = (m == 0 ? bz : (m == 1 ? br : bh));
                const float4* row = (const float4*)(Wm + i * HIDDEN);
                const float4* x4  = (const float4*)xe;
                float ac[4] = {0.f, 0.f, 0.f, 0.f};
                #pragma unroll
                for (int k = 0; k < 25; ++k) {
                    float4 w = row[k], x = x4[k];
                    ac[k & 3] += w.x * x.x + w.y * x.y + w.z * x.z + w.w * x.w;
                }
                a[d * 3 * HIDDEN + t] = bm[i] + ((ac[0] + ac[1]) + (ac[2] + ac[3]));
            }
            __syncthreads();
            if (t == 0)
                __hip_atomic_fetch_add(done, 1, __ATOMIC_RELEASE, __HIP_MEMORY_SCOPE_AGENT);
        }
    }
}

extern "C" void kernel_launch(void* const* d_in, const int* in_sizes, int n_in,
                              void* d_out, int out_size, void* d_ws, size_t ws_size,
                              hipStream_t stream) {
    const float* xvals = (const float*)d_in[0];
    const int*   xidx  = (const int*)d_in[1];
    const int*   tree  = (const int*)d_in[2];
    const int*   npar  = (const int*)d_in[3];
    const float* E     = (const float*)d_in[4];
    const float* Wz    = (const float*)d_in[5];
    const float* Uz    = (const float*)d_in[6];
    const float* bz    = (const float*)d_in[7];
    const float* Wr    = (const float*)d_in[8];
    const float* Ur    = (const float*)d_in[9];
    const float* br    = (const float*)d_in[10];
    const float* Wh    = (const float*)d_in[11];
    const float* Uh    = (const float*)d_in[12];
    const float* bh    = (const float*)d_in[13];
    const float* Wout  = (const float*)d_in[14];
    const float* bout  = (const float*)d_in[15];

    int*   done = (int*)d_ws;
    float* a    = (float*)((char*)d_ws + 1024);

    // re-zero the done counter every call (captured as a graph node)
    hipMemsetAsync(d_ws, 0, 16, stream);

    size_t smem = (size_t)(3 * HIDDEN * PAD + 5000 + 976 + 256) * sizeof(float);
    hipFuncSetAttribute((const void*)k_fused,
                        hipFuncAttributeMaxDynamicSharedMemorySize, (int)smem);

    k_fused<<<NBLK, NTHR, smem, stream>>>(xvals, xidx, tree, npar, E,
                                          Wz, bz, Wr, br, Wh, bh,
                                          Uz, Ur, Uh, Wout, bout,
                                          done, a, (float*)d_out);
}

// Round 4
// 83.144 us; speedup vs baseline: 1.0949x; 1.0949x over previous
//
#include <hip/hip_runtime.h>
#include <math.h>

#define HIDDEN 100
#define NCLASS 4
#define NWORDS 40
#define VOCAB  50000
#define NBLK   48
#define NTHR   512
#define MAXC   24      // chain nodes on the LDS fast path (depth of node 4999 ~ 9-12)
#define PCAP   5120    // parent ids cached in LDS
#define HH     (HIDDEN * HIDDEN)

// ws layout (only used when L > MAXC; written and read by block 0 only):
//   float xe_g[256*HIDDEN]  at byte 0
//   float a_g [256*3*HIDDEN] after

__global__ __launch_bounds__(NTHR) void k_one(
    const float* __restrict__ xvals, const int* __restrict__ xidx,
    const int* __restrict__ tree, const int* __restrict__ np_ptr,
    const float* __restrict__ E,
    const float* __restrict__ Wz, const float* __restrict__ bz,
    const float* __restrict__ Wr, const float* __restrict__ br,
    const float* __restrict__ Wh, const float* __restrict__ bh,
    const float* __restrict__ Uz, const float* __restrict__ Ur,
    const float* __restrict__ Uh,
    const float* __restrict__ Wout, const float* __restrict__ bout,
    float* __restrict__ ws, float* __restrict__ out)
{
    __shared__ int P[PCAP];
    __shared__ int chain[256];
    __shared__ int len_s;
    __shared__ __align__(16) float xe_s[MAXC * HIDDEN];
    __shared__ __align__(16) float a_s[MAXC * 3 * HIDDEN];
    __shared__ __align__(16) float h0[112];
    __shared__ __align__(16) float h1[112];
    __shared__ __align__(16) float zbuf[112];
    __shared__ __align__(16) float rbuf[112];
    __shared__ float ov[16];

    const int t   = threadIdx.x;
    const int bid = blockIdx.x;
    const int npar = np_ptr[0];
    const int pcap = (npar < PCAP) ? npar : PCAP;

    // ---- all blocks: parents -> LDS, chase ancestor chain of node npar-1 ----
    for (int i = t; i < pcap; i += NTHR) P[i] = tree[2 * i];
    __syncthreads();
    if (t == 0) {
        int len = 0, i = npar - 1;
        if (i < 0) i = 0;
        while (i > 0 && len < 255) { chain[len++] = i; i = (i < pcap) ? P[i] : tree[2 * i]; }
        chain[len++] = i;                         // node 0 (zero parent state)
        len_s = len;
    }
    __syncthreads();
    const int L = len_s;

    if (bid > 0) {
        // -------- helpers: warm L3 only; results are sunk, never stored --------
        float sink = 0.f;
        if (bid - 1 < L) {
            // one block per chain node: touch its xidx/xvals and E lines
            int c = chain[bid - 1];
            if (t < 4 * HIDDEN) {
                int h = t >> 2, wg = t & 3;
                const int*   ixp = xidx  + (size_t)c * NWORDS + wg * (NWORDS / 4);
                const float* vp  = xvals + (size_t)c * NWORDS + wg * (NWORDS / 4);
                const float* Eh  = E + (size_t)h * VOCAB;
                #pragma unroll
                for (int w = 0; w < NWORDS / 4; ++w) sink += vp[w] * Eh[ixp[w]];
            }
        } else {
            // remaining blocks: warm U_z/U_r/U_h, W_z/W_r/W_h, W_out
            int wb = bid - 1 - L;
            int nw = NBLK - 1 - L; if (nw < 1) nw = 1;
            const int total = 6 * HH + NCLASS * HIDDEN;
            for (int j = wb * NTHR + t; j < total; j += nw * NTHR) {
                const float* p;
                if      (j <     HH) p = Uz   + j;
                else if (j < 2 * HH) p = Ur   + j -     HH;
                else if (j < 3 * HH) p = Uh   + j - 2 * HH;
                else if (j < 4 * HH) p = Wz   + j - 3 * HH;
                else if (j < 5 * HH) p = Wr   + j - 4 * HH;
                else if (j < 6 * HH) p = Wh   + j - 5 * HH;
                else                 p = Wout + j - 6 * HH;
                sink += *p;
            }
        }
        asm volatile("" :: "v"(sink));            // keep loads live (rule #17)
        return;
    }

    // ================== block 0: the whole computation ==================
    float* xe_g = ws;                             // [256*HIDDEN]   (L>MAXC only)
    float* a_g  = ws + 256 * HIDDEN;              // [256*3*HIDDEN] (L>MAXC only)

    // pre-issue W row (t<300): latency hides under the gather below
    float4 row[25];
    float  bias = 0.f;
    int m3 = 0, ri = 0;
    if (t < 3 * HIDDEN) {
        m3 = t / HIDDEN; ri = t - m3 * HIDDEN;
        const float* Wm = (m3 == 0 ? Wz : (m3 == 1 ? Wr : Wh));
        const float4* w4 = (const float4*)(Wm + ri * HIDDEN);
        #pragma unroll
        for (int k = 0; k < 25; ++k) row[k] = w4[k];
        bias = (m3 == 0 ? bz : (m3 == 1 ? br : bh))[ri];
    }

    // ---- gather: xe[d][h] = sum_w val[w] * E[h, idx[w]] ----
    // task u = d*400 + h*4 + wg ; 4 wg-lanes adjacent -> in-register shfl reduce
    const int ntask = L * 4 * HIDDEN;
    for (int u = t; u < ntask; u += NTHR) {
        int d   = u / (4 * HIDDEN);
        int rem = u - d * 4 * HIDDEN;
        int h = rem >> 2, wg = rem & 3;
        int c = chain[d];
        const int*   ixp = xidx  + (size_t)c * NWORDS + wg * (NWORDS / 4);
        const float* vp  = xvals + (size_t)c * NWORDS + wg * (NWORDS / 4);
        int   ix[NWORDS / 4];
        float vv[NWORDS / 4];
        #pragma unroll
        for (int w = 0; w < NWORDS / 4; ++w) ix[w] = ixp[w];
        #pragma unroll
        for (int w = 0; w < NWORDS / 4; ++w) vv[w] = vp[w];
        const float* Eh = E + (size_t)h * VOCAB;
        float s0 = 0.f, s1 = 0.f;
        #pragma unroll
        for (int w = 0; w < NWORDS / 4; ++w) {
            float p = vv[w] * Eh[ix[w]];
            if (w & 1) s1 += p; else s0 += p;
        }
        float p = s0 + s1;
        p += __shfl_xor(p, 1);
        p += __shfl_xor(p, 2);
        if (wg == 0) {
            if (d < MAXC) xe_s[d * HIDDEN + h] = p;
            else          xe_g[d * HIDDEN + h] = p;
        }
    }
    __syncthreads();

    // ---- a[d][m,i] = b_m[i] + W_m[i,:] . xe[d]  (W row in registers) ----
    for (int d = 0; d < L; ++d) {
        if (t < 3 * HIDDEN) {
            float acc = 0.f;
            if (d < MAXC) {
                const float4* x4 = (const float4*)(xe_s + d * HIDDEN);   // broadcast reads
                #pragma unroll
                for (int k = 0; k < 25; ++k) {
                    float4 w = row[k], x = x4[k];
                    acc += w.x * x.x + w.y * x.y + w.z * x.z + w.w * x.w;
                }
            } else {
                const float4* x4 = (const float4*)(xe_g + d * HIDDEN);
                #pragma unroll
                for (int k = 0; k < 25; ++k) {
                    float4 w = row[k], x = x4[k];
                    acc += w.x * x.x + w.y * x.y + w.z * x.z + w.w * x.w;
                }
            }
            float v = bias + acc;
            if (d < MAXC) a_s[d * 3 * HIDDEN + t] = v;
            else          a_g [d * 3 * HIDDEN + t] = v;
        }
    }

    // ---- reload row[] with the U_m row; init h ----
    if (t < 3 * HIDDEN) {
        const float* Um = (m3 == 0 ? Uz : (m3 == 1 ? Ur : Uh));
        const float4* u4 = (const float4*)(Um + ri * HIDDEN);
        #pragma unroll
        for (int k = 0; k < 25; ++k) row[k] = u4[k];
    }
    if (t < 112) { h0[t] = 0.f; h1[t] = 0.f; }
    __syncthreads();

    // ---- GRU recurrence over the chain, root-first ----
    float* hc = h0;
    float* hn = h1;
    for (int d = L - 1; d >= 0; --d) {
        const bool  fast = (d < MAXC);
        const float* ad  = (fast ? a_s : a_g) + d * 3 * HIDDEN;
        if (t < 2 * HIDDEN) {                      // z and r rows (U row in regs)
            float acc = ad[t];
            const float4* h4 = (const float4*)hc;  // broadcast
            #pragma unroll
            for (int k = 0; k < 25; ++k) {
                float4 u = row[k], h = h4[k];
                acc += u.x * h.x + u.y * h.y + u.z * h.z + u.w * h.w;
            }
            acc = fminf(fmaxf(acc, 0.f), 1.f);     // Hardtanh(0,1)
            if (t < HIDDEN) zbuf[t] = acc;                        // z
            else            rbuf[t - HIDDEN] = acc * hc[t - HIDDEN]; // r * parent_h
        }
        __syncthreads();
        if (t >= 2 * HIDDEN && t < 3 * HIDDEN) {   // c row + state update
            int ii = t - 2 * HIDDEN;
            float acc = ad[t];
            const float4* r4 = (const float4*)rbuf; // broadcast
            #pragma unroll
            for (int k = 0; k < 25; ++k) {
                float4 u = row[k], h = r4[k];
                acc += u.x * h.x + u.y * h.y + u.z * h.z + u.w * h.w;
            }
            float c = tanhf(acc);
            float z = zbuf[ii];
            hn[ii] = (1.f - z) * hc[ii] + z * c;
        }
        __syncthreads();
        float* tmp = hc; hc = hn; hn = tmp;
    }

    // ---- out = softmax(W_out @ h + b_out) ----
    if (t < NCLASS) {
        float acc = bout[t];
        const float* wr = Wout + t * HIDDEN;
        for (int j = 0; j < HIDDEN; ++j) acc += wr[j] * hc[j];
        ov[t] = acc;
    }
    __syncthreads();
    if (t == 0) {
        float mx = fmaxf(fmaxf(ov[0], ov[1]), fmaxf(ov[2], ov[3]));
        float e0 = expf(ov[0] - mx), e1 = expf(ov[1] - mx);
        float e2 = expf(ov[2] - mx), e3 = expf(ov[3] - mx);
        float s = e0 + e1 + e2 + e3;
        out[0] = e0 / s; out[1] = e1 / s; out[2] = e2 / s; out[3] = e3 / s;
    }
}

extern "C" void kernel_launch(void* const* d_in, const int* in_sizes, int n_in,
                              void* d_out, int out_size, void* d_ws, size_t ws_size,
                              hipStream_t stream) {
    const float* xvals = (const float*)d_in[0];
    const int*   xidx  = (const int*)d_in[1];
    const int*   tree  = (const int*)d_in[2];
    const int*   npar  = (const int*)d_in[3];
    const float* E     = (const float*)d_in[4];
    const float* Wz    = (const float*)d_in[5];
    const float* Uz    = (const float*)d_in[6];
    const float* bz    = (const float*)d_in[7];
    const float* Wr    = (const float*)d_in[8];
    const float* Ur    = (const float*)d_in[9];
    const float* br    = (const float*)d_in[10];
    const float* Wh    = (const float*)d_in[11];
    const float* Uh    = (const float*)d_in[12];
    const float* bh    = (const float*)d_in[13];
    const float* Wout  = (const float*)d_in[14];
    const float* bout  = (const float*)d_in[15];

    k_one<<<NBLK, NTHR, 0, stream>>>(xvals, xidx, tree, npar, E,
                                     Wz, bz, Wr, br, Wh, bh,
                                     Uz, Ur, Uh, Wout, bout,
                                     (float*)d_ws, (float*)d_out);
}

// Round 5
// 28.720 us; speedup vs baseline: 3.1698x; 2.8950x over previous
//
#include <hip/hip_runtime.h>
#include <math.h>

#define HIDDEN   100
#define NCLASS   4
#define NWORDS   40
#define VOCAB    50000
#define PCAP     5120
#define MAXC     24        // chain nodes of a[] staged in GRU LDS (L expected ~10)
#define MAXCHAIN 200
#define NTHR     640
#define PREP_BLKS 48

// ws layout: byte 0: int len; byte 64: float a[MAXCHAIN][3*HIDDEN]

__global__ __launch_bounds__(NTHR) void k_prep(
    const float* __restrict__ xvals, const int* __restrict__ xidx,
    const int* __restrict__ tree, const int* __restrict__ np_ptr,
    const float* __restrict__ E,
    const float* __restrict__ Wz, const float* __restrict__ bz,
    const float* __restrict__ Wr, const float* __restrict__ br,
    const float* __restrict__ Wh, const float* __restrict__ bh,
    int* __restrict__ len_out, float* __restrict__ a)
{
    __shared__ int P[PCAP];
    __shared__ int chain[MAXCHAIN];
    __shared__ int len_s;
    __shared__ __align__(16) float xe[HIDDEN + 4];

    const int t = threadIdx.x;
    const int npar = np_ptr[0];
    const int pcap = (npar < PCAP) ? npar : PCAP;

    // W half-row preload: 25 independent float2 loads, latency hides under staging+chase
    float2 wreg[25];
    float bias = 0.f;
    int row = 0, half = t & 1;
    if (t < 600) {
        row = t >> 1;
        int m = row / HIDDEN, ri = row - m * HIDDEN;
        const float* Wm = (m == 0 ? Wz : (m == 1 ? Wr : Wh));
        const float2* w2 = (const float2*)(Wm + ri * HIDDEN + half * 50);
        #pragma unroll
        for (int k = 0; k < 25; ++k) wreg[k] = w2[k];
        if (half == 0) bias = (m == 0 ? bz : (m == 1 ? br : bh))[ri];
    }

    // parents -> LDS, chase ancestor chain of node npar-1 (every block)
    for (int i = t; i < pcap; i += NTHR) P[i] = tree[2 * i];
    __syncthreads();
    if (t == 0) {
        int len = 0, i = npar - 1; if (i < 0) i = 0;
        while (i > 0 && len < MAXCHAIN - 1) { chain[len++] = i; i = (i < pcap) ? P[i] : tree[2 * i]; }
        chain[len++] = i;                       // node 0 (zero parent state)
        len_s = len;
        if (blockIdx.x == 0) *len_out = len;
    }
    __syncthreads();
    const int L = len_s;

    for (int d = blockIdx.x; d < L; d += gridDim.x) {
        const int c = chain[d];
        // xe[h] = sum_w val[w] * E[h, idx[w]] : 400 units, quad shfl reduce
        if (t < 4 * HIDDEN) {
            int h = t >> 2, wg = t & 3;
            const int*   ixp = xidx  + (size_t)c * NWORDS + wg * 10;
            const float* vp  = xvals + (size_t)c * NWORDS + wg * 10;
            int ix[10]; float vv[10];
            #pragma unroll
            for (int w = 0; w < 10; ++w) ix[w] = ixp[w];
            #pragma unroll
            for (int w = 0; w < 10; ++w) vv[w] = vp[w];
            const float* Eh = E + (size_t)h * VOCAB;
            float s0 = 0.f, s1 = 0.f;
            #pragma unroll
            for (int w = 0; w < 10; ++w) {
                float p = vv[w] * Eh[ix[w]];
                if (w & 1) s1 += p; else s0 += p;
            }
            float p = s0 + s1;
            p += __shfl_xor(p, 1);
            p += __shfl_xor(p, 2);
            if (wg == 0) xe[h] = p;
        }
        __syncthreads();
        // a[d][row] = b[row] + W[row,:] . xe  : 600 half-row units
        if (t < 600) {
            const float2* x2 = (const float2*)(xe + half * 50);
            float a0 = 0.f, a1 = 0.f;
            #pragma unroll
            for (int k = 0; k < 25; ++k) {
                float2 w = wreg[k], x = x2[k];
                a0 += w.x * x.x; a1 += w.y * x.y;
            }
            float p = a0 + a1;
            p += __shfl_xor(p, 1);
            if (half == 0) a[d * 3 * HIDDEN + row] = p + bias;
        }
        __syncthreads();
    }
}

__global__ __launch_bounds__(NTHR) void k_gru(
    const float* __restrict__ Uz, const float* __restrict__ Ur,
    const float* __restrict__ Uh,
    const float* __restrict__ Wout, const float* __restrict__ bout,
    const int* __restrict__ len_p, const float* __restrict__ a,
    float* __restrict__ out)
{
    __shared__ __align__(16) float a_lds[MAXC * 3 * HIDDEN];   // 28.8 KB
    __shared__ __align__(16) float h0[112], h1[112], zbuf[112], rbuf[112];
    __shared__ float ov[NCLASS];

    const int t = threadIdx.x;
    const int half = t & 1;

    // U half-row preload (independent, issue first)
    // rows: t<400 -> rows 0..199 (U_z,U_r); 400<=t<600 -> rows 200..299 (U_h)
    float2 ureg[25];
    int grow = 0;
    if (t < 600) {
        grow = (t < 400) ? (t >> 1) : (200 + ((t - 400) >> 1));
        int m = grow / HIDDEN, ri = grow - m * HIDDEN;
        const float* Um = (m == 0 ? Uz : (m == 1 ? Ur : Uh));
        const float2* u2 = (const float2*)(Um + ri * HIDDEN + half * 50);
        #pragma unroll
        for (int k = 0; k < 25; ++k) ureg[k] = u2[k];
    }
    // optimistic batched prefetch of a[0..MAXC*300) (beyond L*300 is unread garbage)
    float ar[12];
    #pragma unroll
    for (int j = 0; j < 12; ++j) {
        int k = t + j * NTHR;
        if (k < MAXC * 3 * HIDDEN) ar[j] = a[k];
    }
    const int L = *len_p;
    #pragma unroll
    for (int j = 0; j < 12; ++j) {
        int k = t + j * NTHR;
        if (k < MAXC * 3 * HIDDEN) a_lds[k] = ar[j];
    }
    if (t < 112) { h0[t] = 0.f; h1[t] = 0.f; }
    __syncthreads();

    float* hc = h0;
    float* hn = h1;
    for (int d = L - 1; d >= 0; --d) {
        const float* ad = (d < MAXC) ? (a_lds + d * 3 * HIDDEN) : (a + d * 3 * HIDDEN);
        if (t < 400) {                           // z and r rows (0..199)
            const float2* h2 = (const float2*)(hc + half * 50);   // 2-addr broadcast, conflict-free
            float a0 = 0.f, a1 = 0.f;
            #pragma unroll
            for (int k = 0; k < 25; ++k) {
                float2 u = ureg[k], x = h2[k];
                a0 += u.x * x.x; a1 += u.y * x.y;
            }
            float p = a0 + a1;
            p += __shfl_xor(p, 1);
            if (half == 0) {
                float v = fminf(fmaxf(ad[grow] + p, 0.f), 1.f);   // Hardtanh(0,1)
                if (grow < HIDDEN) zbuf[grow] = v;                // z
                else               rbuf[grow - HIDDEN] = v * hc[grow - HIDDEN]; // r*h
            }
        }
        __syncthreads();
        if (t >= 400 && t < 600) {               // c rows (200..299) + state update
            const float2* r2 = (const float2*)(rbuf + half * 50);
            float a0 = 0.f, a1 = 0.f;
            #pragma unroll
            for (int k = 0; k < 25; ++k) {
                float2 u = ureg[k], x = r2[k];
                a0 += u.x * x.x; a1 += u.y * x.y;
            }
            float p = a0 + a1;
            p += __shfl_xor(p, 1);
            if (half == 0) {
                int i = grow - 200;
                float c = tanhf(ad[grow] + p);
                float z = zbuf[i];
                hn[i] = (1.f - z) * hc[i] + z * c;
            }
        }
        __syncthreads();
        float* tmp = hc; hc = hn; hn = tmp;
    }

    if (t < NCLASS) {
        float acc = bout[t];
        const float* wr = Wout + t * HIDDEN;
        for (int j = 0; j < HIDDEN; ++j) acc += wr[j] * hc[j];
        ov[t] = acc;
    }
    __syncthreads();
    if (t == 0) {
        float mx = fmaxf(fmaxf(ov[0], ov[1]), fmaxf(ov[2], ov[3]));
        float e0 = expf(ov[0] - mx), e1 = expf(ov[1] - mx);
        float e2 = expf(ov[2] - mx), e3 = expf(ov[3] - mx);
        float s = e0 + e1 + e2 + e3;
        out[0] = e0 / s; out[1] = e1 / s; out[2] = e2 / s; out[3] = e3 / s;
    }
}

extern "C" void kernel_launch(void* const* d_in, const int* in_sizes, int n_in,
                              void* d_out, int out_size, void* d_ws, size_t ws_size,
                              hipStream_t stream) {
    const float* xvals = (const float*)d_in[0];
    const int*   xidx  = (const int*)d_in[1];
    const int*   tree  = (const int*)d_in[2];
    const int*   npar  = (const int*)d_in[3];
    const float* E     = (const float*)d_in[4];
    const float* Wz    = (const float*)d_in[5];
    const float* Uz    = (const float*)d_in[6];
    const float* bz    = (const float*)d_in[7];
    const float* Wr    = (const float*)d_in[8];
    const float* Ur    = (const float*)d_in[9];
    const float* br    = (const float*)d_in[10];
    const float* Wh    = (const float*)d_in[11];
    const float* Uh    = (const float*)d_in[12];
    const float* bh    = (const float*)d_in[13];
    const float* Wout  = (const float*)d_in[14];
    const float* bout  = (const float*)d_in[15];

    int*   len = (int*)d_ws;
    float* a   = (float*)((char*)d_ws + 64);

    k_prep<<<PREP_BLKS, NTHR, 0, stream>>>(xvals, xidx, tree, npar, E,
                                           Wz, bz, Wr, br, Wh, bh, len, a);
    k_gru<<<1, NTHR, 0, stream>>>(Uz, Ur, Uh, Wout, bout, len, a, (float*)d_out);
}